// Round 20
// baseline (38.255 us; speedup 1.0000x reference)
//
#include <hip/hip_runtime.h>
#include <hip/hip_fp16.h>

#define B_  64
#define L_  512
#define D_  768
#define S_  64
#define N1_ 384
#define N2_ 128

typedef __attribute__((ext_vector_type(8))) _Float16 half8;
typedef __attribute__((ext_vector_type(8))) short short8v;
typedef __attribute__((ext_vector_type(4))) float f32x4;

__device__ __forceinline__ ushort f2h(float x) {
  return __half_as_ushort(__float2half_rn(x));
}

// ---------------------------------------------------------------------------
// ONE launch, 288 blocks x 512 thr:
//  blocks 0..31: weight swizzle (R13-proven fragment layout), then ONE
//    release-signal each on q[0]. No LDS use.
//  blocks 32..287: R16's EXACT fused mean+MLP quarter-sample body. The only
//    addition: after the ~18us stream phase, tid0 acquire-spins until
//    q[0]==32 (always already true by then -> exits on first read).
//  Deadlock-free by co-residency: 288 blocks, 40KB LDS, <=52 VGPR ->
//  >=2 blocks/CU capacity (512 needed >= 288), all resident from t=0.
// ---------------------------------------------------------------------------
__global__ __launch_bounds__(512, 1) void mega_kernel(
    const float* __restrict__ hidden, const int* __restrict__ seg_ids,
    const float* __restrict__ W1, const float* __restrict__ b1,
    const float* __restrict__ W2, const float* __restrict__ b2,
    const float* __restrict__ W3, const float* __restrict__ b3,
    ushort* __restrict__ w1s, ushort* __restrict__ w2s,
    unsigned int* __restrict__ q, float* __restrict__ out) {
  const int bid0 = blockIdx.x;
  const int tid  = threadIdx.x;

  if (bid0 < 32) {
    // ================= weight swizzle (producer) =================
    if (bid0 < 24) {
      const int n0 = bid0 * 16;
      #pragma unroll
      for (int i = 0; i < 3; ++i) {
        const int slot = i * 512 + tid;        // 0..1535
        const int kt = slot >> 6, l = slot & 63;
        short8v r;
        #pragma unroll
        for (int e = 0; e < 8; ++e) {
          float x = W1[(size_t)(kt * 32 + ((l >> 4) << 3) + e) * N1_ + n0 + (l & 15)];
          r[e] = (short)f2h(x);
        }
        *(short8v*)(w1s + ((size_t)bid0 * 1536 + slot) * 8) = r;
      }
    } else {
      const int wb = bid0 - 24;
      const int n0 = wb * 16;
      #pragma unroll
      for (int i = 0; i < 2; ++i) {
        const int slot = i * 512 + tid;        // 0..1023, use <768
        if (slot < 768) {
          const int kt = slot >> 6, l = slot & 63;
          short8v r;
          #pragma unroll
          for (int e = 0; e < 8; ++e) {
            float x = W2[(size_t)(kt * 32 + ((l >> 4) << 3) + e) * N2_ + n0 + (l & 15)];
            r[e] = (short)f2h(x);
          }
          *(short8v*)(w2s + ((size_t)wb * 768 + slot) * 8) = r;
        }
      }
    }
    __syncthreads();
    if (tid == 0) {
      __threadfence();
      __hip_atomic_fetch_add(q, 1u, __ATOMIC_RELEASE, __HIP_MEMORY_SCOPE_AGENT);
    }
    return;
  }

  // ================= fused mean+MLP (R16 body, consumer) =================
  __shared__ __align__(16) char lds[39584];
  int*    sids = (int*)lds;                     // 2048 B
  ushort* sM   = (ushort*)(lds + 2048);         // [16][776] = 24832 B
  ushort* sH   = (ushort*)(lds + 26880);        // [16][392] = 12544 B
  float*  pl   = (float*)(lds + 39424);         // 32 floats
  int*    wred = (int*)(lds + 39552);           // 4 ints

  const int bid  = bid0 - 32;
  const int wid  = tid >> 6;
  const int lane = tid & 63;
  const int lrow = lane & 15;
  const int lk   = (lane >> 4) * 8;
  const int b    = bid >> 2;
  const int qs   = bid & 3;
  const int s0   = qs * 16;
  const int row0 = b * 64 + s0;

  if (tid < 128)
    ((int4*)sids)[tid] = ((const int4*)(seg_ids + b * L_))[tid];
  if (tid < 32) pl[tid] = 0.0f;
  __syncthreads();

  // ---- bounds per 8-segment group (g=0,1; threads 384..511 idle) ----
  const int g  = tid / 192;
  const int gt = tid - g * 192;
  if (g < 2) {
    const int s0g = s0 + g * 8;
    int pk = 0;
    if (gt < 128) {
      int4 v = ((const int4*)sids)[gt];
      int clo = (v.x < s0g) + (v.y < s0g) + (v.z < s0g) + (v.w < s0g);
      int chi = (v.x < s0g + 8) + (v.y < s0g + 8) +
                (v.z < s0g + 8) + (v.w < s0g + 8);
      pk = clo * 1024 + chi;
    }
    #pragma unroll
    for (int off = 1; off < 64; off <<= 1) pk += __shfl_xor(pk, off);
    if (gt < 128 && (gt & 63) == 0) wred[g * 2 + (gt >> 6)] = pk;
  }
  __syncthreads();

  // ---- stream this group's 8 segments' token span -> sM rows ----
  if (g < 2) {
    const int s0g = s0 + g * 8;
    const int tot = wred[g * 2] + wred[g * 2 + 1];
    const int lo = tot >> 10;
    const int hi = tot & 1023;

    const float4* hp = (const float4*)(hidden + (size_t)b * L_ * D_) + gt;
    const uint2 zz = {0u, 0u};

    int cur = (lo < hi) ? sids[lo] : s0g + 8;
    for (int z = s0g; z < cur; ++z)
      *(uint2*)(sM + (z - s0) * 776 + gt * 4) = zz;

    float4 acc = {0.0f, 0.0f, 0.0f, 0.0f};
    int segstart = lo;
    for (int l = lo; l < hi; l += 8) {
      float4 v[8];
      int sv[8];
      #pragma unroll
      for (int k = 0; k < 8; ++k) {
        v[k]  = hp[(size_t)min(l + k, hi - 1) * (D_ / 4)];
        sv[k] = sids[min(l + k + 1, hi - 1)];
      }
      #pragma unroll
      for (int k = 0; k < 8; ++k) {
        if (l + k < hi) {
          acc.x += v[k].x; acc.y += v[k].y;
          acc.z += v[k].z; acc.w += v[k].w;
          const int nx = l + k + 1;
          if (nx == hi || sv[k] != cur) {
            const float inv = 1.0f / (float)(nx - segstart);
            ushort4 h;
            h.x = f2h(acc.x * inv); h.y = f2h(acc.y * inv);
            h.z = f2h(acc.z * inv); h.w = f2h(acc.w * inv);
            *(ushort4*)(sM + (cur - s0) * 776 + gt * 4) = h;
            const int nxt = (nx == hi) ? s0g + 8 : sv[k];
            for (int z = cur + 1; z < nxt; ++z)
              *(uint2*)(sM + (z - s0) * 776 + gt * 4) = zz;
            acc.x = 0.0f; acc.y = 0.0f; acc.z = 0.0f; acc.w = 0.0f;
            segstart = nx; cur = nxt;
          }
        }
      }
    }
  }
  __syncthreads();

  // ---- gate: weights ready? (stream took ~18us; signal done by ~3us) ----
  if (tid == 0) {
    while (__hip_atomic_load(q, __ATOMIC_ACQUIRE, __HIP_MEMORY_SCOPE_AGENT) < 32u)
      __builtin_amdgcn_s_sleep(2);
  }
  __syncthreads();

  // ---- phase 1: 24 barrier-free k-tiles; wave owns W1 ntiles 3w..3w+2 ----
  f32x4 acc1[3] = {};
  {
    const ushort* bp = w1s + (size_t)(3 * wid) * 24 * 512 + lane * 8;
    #pragma unroll 4
    for (int kt = 0; kt < 24; ++kt) {
      half8 af = *(const half8*)&sM[lrow * 776 + kt * 32 + lk];
      half8 bf[3];
      #pragma unroll
      for (int j = 0; j < 3; ++j)
        bf[j] = *(const half8*)(bp + ((size_t)j * 24 + kt) * 512);
      #pragma unroll
      for (int j = 0; j < 3; ++j)
        acc1[j] = __builtin_amdgcn_mfma_f32_16x16x32_f16(af, bf[j], acc1[j], 0, 0, 0);
    }
  }
  #pragma unroll
  for (int j = 0; j < 3; ++j) {
    const int n = (3 * wid + j) * 16 + lrow;
    const float bj = b1[n];
    #pragma unroll
    for (int r = 0; r < 4; ++r) {
      const int m = (lane >> 4) * 4 + r;
      sH[m * 392 + n] = f2h(fmaxf(acc1[j][r] + bj, 0.0f));
    }
  }
  __syncthreads();

  // ---- phase 2: 12 k-tiles; wave owns W2 ntile = wid ----
  f32x4 a2 = {};
  {
    const ushort* bp = w2s + (size_t)wid * 12 * 512 + lane * 8;
    #pragma unroll 4
    for (int kt = 0; kt < 12; ++kt) {
      half8 af = *(const half8*)&sH[lrow * 392 + kt * 32 + lk];
      half8 bf = *(const half8*)(bp + (size_t)kt * 512);
      a2 = __builtin_amdgcn_mfma_f32_16x16x32_f16(af, bf, a2, 0, 0, 0);
    }
  }

  // ---- epilogue: h2 = relu(a2 + b2); logits = h2 @ W3 + b3 ----
  const int col = wid * 16 + lrow;
  const float w30 = W3[col * 2 + 0];
  const float w31 = W3[col * 2 + 1];
  const float b2v = b2[col];
  #pragma unroll
  for (int r = 0; r < 4; ++r) {
    float v = fmaxf(a2[r] + b2v, 0.0f);
    float p0 = v * w30;
    float p1 = v * w31;
    p0 += __shfl_xor(p0, 1); p1 += __shfl_xor(p1, 1);
    p0 += __shfl_xor(p0, 2); p1 += __shfl_xor(p1, 2);
    p0 += __shfl_xor(p0, 4); p1 += __shfl_xor(p1, 4);
    p0 += __shfl_xor(p0, 8); p1 += __shfl_xor(p1, 8);
    if (lrow == 0) {
      const int row = (lane >> 4) * 4 + r;   // 0..15
      atomicAdd(&pl[row * 2 + 0], p0);
      atomicAdd(&pl[row * 2 + 1], p1);
    }
  }
  __syncthreads();
  if (tid < 32) {
    const int row = tid >> 1, c = tid & 1;
    out[(size_t)(row0 + row) * 2 + c] = pl[tid] + b3[c];
  }
}

// ---------------------------------------------------------------------------
extern "C" void kernel_launch(void* const* d_in, const int* in_sizes, int n_in,
                              void* d_out, int out_size, void* d_ws, size_t ws_size,
                              hipStream_t stream) {
  const float* hidden  = (const float*)d_in[0];
  const int*   seg_ids = (const int*)d_in[1];
  const float* W1 = (const float*)d_in[2];
  const float* b1 = (const float*)d_in[3];
  const float* W2 = (const float*)d_in[4];
  const float* b2 = (const float*)d_in[5];
  const float* W3 = (const float*)d_in[6];
  const float* b3 = (const float*)d_in[7];
  float* out = (float*)d_out;

  char* p = (char*)d_ws;
  ushort* w1s = (ushort*)p;  p += (size_t)N1_ * D_ * 2;     // 0.59 MB swizzled
  ushort* w2s = (ushort*)p;  p += (size_t)N2_ * N1_ * 2;    // 98 KB swizzled
  unsigned int* q = (unsigned int*)p;

  hipMemsetAsync(q, 0, sizeof(unsigned int), stream);
  mega_kernel<<<288, 512, 0, stream>>>(
      hidden, seg_ids, W1, b1, W2, b2, W3, b3, w1s, w2s, q, out);
}

// Round 21
// 34.532 us; speedup vs baseline: 1.1078x; 1.1078x over previous
//
#include <hip/hip_runtime.h>
#include <hip/hip_fp16.h>

#define B_  64
#define L_  512
#define D_  768
#define S_  64
#define N1_ 384
#define N2_ 128

typedef __attribute__((ext_vector_type(8))) _Float16 half8;
typedef __attribute__((ext_vector_type(8))) short short8v;
typedef __attribute__((ext_vector_type(4))) float f32x4;

__device__ __forceinline__ ushort f2h(float x) {
  return __half_as_ushort(__float2half_rn(x));
}

// ---------------------------------------------------------------------------
// Kernel A: weight swizzle to MFMA B-fragment lane order (proven R13/R14).
// blob(ntile,kt)[lane][e] = W[kt*32+(lane>>4)*8+e][ntile*16+(lane&15)].
// Blocks 0..23 -> W1 ntiles; 24..31 -> W2 ntiles.
// ---------------------------------------------------------------------------
__global__ __launch_bounds__(192) void wswz_kernel(
    const float* __restrict__ W1, ushort* __restrict__ w1s,
    const float* __restrict__ W2, ushort* __restrict__ w2s) {
  const int bid = blockIdx.x;
  const int tid = threadIdx.x;
  if (bid < 24) {
    const int n0 = bid * 16;
    #pragma unroll 1
    for (int i = 0; i < 8; ++i) {
      const int slot = i * 192 + tid;          // 0..1535
      const int kt = slot >> 6, l = slot & 63;
      short8v r;
      #pragma unroll
      for (int e = 0; e < 8; ++e) {
        float x = W1[(size_t)(kt * 32 + ((l >> 4) << 3) + e) * N1_ + n0 + (l & 15)];
        r[e] = (short)f2h(x);
      }
      *(short8v*)(w1s + ((size_t)bid * 1536 + slot) * 8) = r;
    }
  } else {
    const int wb = bid - 24;
    const int n0 = wb * 16;
    #pragma unroll 1
    for (int i = 0; i < 4; ++i) {
      const int slot = i * 192 + tid;          // 0..767
      const int kt = slot >> 6, l = slot & 63;
      short8v r;
      #pragma unroll
      for (int e = 0; e < 8; ++e) {
        float x = W2[(size_t)(kt * 32 + ((l >> 4) << 3) + e) * N2_ + n0 + (l & 15)];
        r[e] = (short)f2h(x);
      }
      *(short8v*)(w2s + ((size_t)wb * 768 + slot) * 8) = r;
    }
  }
}

// ---------------------------------------------------------------------------
// Kernel B: FULLY fused mean+MLP per quarter-sample. 256 blocks x 512 thr.
// (R16 exact — best measured configuration: 34.84 us.)
//  1. seg_ids of sample -> LDS (2 KB).
//  2. Two independent 192-thread groups each stream 8 segments' contiguous
//     token span (R9-proven masked-batch boundary-flush) writing f16 means
//     DIRECTLY into LDS sM[16][776] — means never touch HBM.
//  3. MLP phase1 (24 barrier-free k-tiles, B-frags coalesced from L2-hot
//     swizzled w1s), h1 -> LDS, phase2 + W3 shfl-reduce epilogue -> out.
// ---------------------------------------------------------------------------
__global__ __launch_bounds__(512, 1) void fused_all(
    const float* __restrict__ hidden, const int* __restrict__ seg_ids,
    const ushort* __restrict__ w1s, const float* __restrict__ b1,
    const ushort* __restrict__ w2s, const float* __restrict__ b2,
    const float* __restrict__ W3, const float* __restrict__ b3,
    float* __restrict__ out) {
  __shared__ __align__(16) char lds[39584];
  int*    sids = (int*)lds;                     // 2048 B
  ushort* sM   = (ushort*)(lds + 2048);         // [16][776] = 24832 B
  ushort* sH   = (ushort*)(lds + 26880);        // [16][392] = 12544 B
  float*  pl   = (float*)(lds + 39424);         // 32 floats
  int*    wred = (int*)(lds + 39552);           // 4 ints

  const int tid  = threadIdx.x;
  const int wid  = tid >> 6;
  const int lane = tid & 63;
  const int lrow = lane & 15;
  const int lk   = (lane >> 4) * 8;
  const int b    = blockIdx.x >> 2;
  const int qs   = blockIdx.x & 3;
  const int s0   = qs * 16;
  const int row0 = b * 64 + s0;

  if (tid < 128)
    ((int4*)sids)[tid] = ((const int4*)(seg_ids + b * L_))[tid];
  if (tid < 32) pl[tid] = 0.0f;
  __syncthreads();

  // ---- bounds per 8-segment group (g=0,1; threads 384..511 idle) ----
  const int g  = tid / 192;
  const int gt = tid - g * 192;
  if (g < 2) {
    const int s0g = s0 + g * 8;
    int pk = 0;
    if (gt < 128) {
      int4 v = ((const int4*)sids)[gt];
      int clo = (v.x < s0g) + (v.y < s0g) + (v.z < s0g) + (v.w < s0g);
      int chi = (v.x < s0g + 8) + (v.y < s0g + 8) +
                (v.z < s0g + 8) + (v.w < s0g + 8);
      pk = clo * 1024 + chi;
    }
    #pragma unroll
    for (int off = 1; off < 64; off <<= 1) pk += __shfl_xor(pk, off);
    if (gt < 128 && (gt & 63) == 0) wred[g * 2 + (gt >> 6)] = pk;
  }
  __syncthreads();

  // ---- stream means for this group's 8 segments into sM ----
  if (g < 2) {
    const int s0g = s0 + g * 8;
    const int tot = wred[g * 2] + wred[g * 2 + 1];
    const int lo = tot >> 10;
    const int hi = tot & 1023;

    const float4* hp = (const float4*)(hidden + (size_t)b * L_ * D_) + gt;
    const uint2 zz = {0u, 0u};

    int cur = (lo < hi) ? sids[lo] : s0g + 8;
    for (int z = s0g; z < cur; ++z)
      *(uint2*)(sM + (z - s0) * 776 + gt * 4) = zz;

    float4 acc = {0.0f, 0.0f, 0.0f, 0.0f};
    int segstart = lo;
    for (int l = lo; l < hi; l += 8) {
      float4 v[8];
      int sv[8];
      #pragma unroll
      for (int k = 0; k < 8; ++k) {
        v[k]  = hp[(size_t)min(l + k, hi - 1) * (D_ / 4)];
        sv[k] = sids[min(l + k + 1, hi - 1)];
      }
      #pragma unroll
      for (int k = 0; k < 8; ++k) {
        if (l + k < hi) {
          acc.x += v[k].x; acc.y += v[k].y;
          acc.z += v[k].z; acc.w += v[k].w;
          const int nx = l + k + 1;
          if (nx == hi || sv[k] != cur) {
            const float inv = 1.0f / (float)(nx - segstart);
            ushort4 h;
            h.x = f2h(acc.x * inv); h.y = f2h(acc.y * inv);
            h.z = f2h(acc.z * inv); h.w = f2h(acc.w * inv);
            *(ushort4*)(sM + (cur - s0) * 776 + gt * 4) = h;
            const int nxt = (nx == hi) ? s0g + 8 : sv[k];
            for (int z = cur + 1; z < nxt; ++z)
              *(uint2*)(sM + (z - s0) * 776 + gt * 4) = zz;
            acc.x = 0.0f; acc.y = 0.0f; acc.z = 0.0f; acc.w = 0.0f;
            segstart = nx; cur = nxt;
          }
        }
      }
    }
  }
  __syncthreads();

  // ---- phase 1: 24 k-tiles, no barriers; wave owns W1 ntiles 3w..3w+2 ----
  f32x4 acc1[3] = {};
  {
    const ushort* bp = w1s + (size_t)(3 * wid) * 24 * 512 + lane * 8;
    #pragma unroll 4
    for (int kt = 0; kt < 24; ++kt) {
      half8 af = *(const half8*)&sM[lrow * 776 + kt * 32 + lk];
      half8 bf[3];
      #pragma unroll
      for (int j = 0; j < 3; ++j)
        bf[j] = *(const half8*)(bp + ((size_t)j * 24 + kt) * 512);
      #pragma unroll
      for (int j = 0; j < 3; ++j)
        acc1[j] = __builtin_amdgcn_mfma_f32_16x16x32_f16(af, bf[j], acc1[j], 0, 0, 0);
    }
  }
  #pragma unroll
  for (int j = 0; j < 3; ++j) {
    const int n = (3 * wid + j) * 16 + lrow;
    const float bj = b1[n];
    #pragma unroll
    for (int r = 0; r < 4; ++r) {
      const int m = (lane >> 4) * 4 + r;
      sH[m * 392 + n] = f2h(fmaxf(acc1[j][r] + bj, 0.0f));
    }
  }
  __syncthreads();

  // ---- phase 2: 12 k-tiles; wave owns W2 ntile = wid ----
  f32x4 a2 = {};
  {
    const ushort* bp = w2s + (size_t)wid * 12 * 512 + lane * 8;
    #pragma unroll 4
    for (int kt = 0; kt < 12; ++kt) {
      half8 af = *(const half8*)&sH[lrow * 392 + kt * 32 + lk];
      half8 bf = *(const half8*)(bp + (size_t)kt * 512);
      a2 = __builtin_amdgcn_mfma_f32_16x16x32_f16(af, bf, a2, 0, 0, 0);
    }
  }

  // ---- epilogue: h2 = relu(a2 + b2); logits = h2 @ W3 + b3 ----
  const int col = wid * 16 + lrow;
  const float w30 = W3[col * 2 + 0];
  const float w31 = W3[col * 2 + 1];
  const float b2v = b2[col];
  #pragma unroll
  for (int r = 0; r < 4; ++r) {
    float v = fmaxf(a2[r] + b2v, 0.0f);
    float p0 = v * w30;
    float p1 = v * w31;
    p0 += __shfl_xor(p0, 1); p1 += __shfl_xor(p1, 1);
    p0 += __shfl_xor(p0, 2); p1 += __shfl_xor(p1, 2);
    p0 += __shfl_xor(p0, 4); p1 += __shfl_xor(p1, 4);
    p0 += __shfl_xor(p0, 8); p1 += __shfl_xor(p1, 8);
    if (lrow == 0) {
      const int row = (lane >> 4) * 4 + r;   // 0..15
      atomicAdd(&pl[row * 2 + 0], p0);
      atomicAdd(&pl[row * 2 + 1], p1);
    }
  }
  __syncthreads();
  if (tid < 32) {
    const int row = tid >> 1, c = tid & 1;
    out[(size_t)(row0 + row) * 2 + c] = pl[tid] + b3[c];
  }
}

// ---------------------------------------------------------------------------
extern "C" void kernel_launch(void* const* d_in, const int* in_sizes, int n_in,
                              void* d_out, int out_size, void* d_ws, size_t ws_size,
                              hipStream_t stream) {
  const float* hidden  = (const float*)d_in[0];
  const int*   seg_ids = (const int*)d_in[1];
  const float* W1 = (const float*)d_in[2];
  const float* b1 = (const float*)d_in[3];
  const float* W2 = (const float*)d_in[4];
  const float* b2 = (const float*)d_in[5];
  const float* W3 = (const float*)d_in[6];
  const float* b3 = (const float*)d_in[7];
  float* out = (float*)d_out;

  char* p = (char*)d_ws;
  ushort* w1s = (ushort*)p;  p += (size_t)N1_ * D_ * 2;     // 0.59 MB swizzled
  ushort* w2s = (ushort*)p;  p += (size_t)N2_ * N1_ * 2;    // 98 KB swizzled

  wswz_kernel<<<32, 192, 0, stream>>>(W1, w1s, W2, w2s);
  fused_all<<<B_ * 4, 512, 0, stream>>>(
      hidden, seg_ids, w1s, b1, w2s, b2, W3, b3, out);
}